// Round 1
// baseline (238.655 us; speedup 1.0000x reference)
//
#include <hip/hip_runtime.h>
#include <stdint.h>

#define BATCH 2
#define SEQ 2048
#define DM 1024
#define NH 16
#define HD 64
#define QR 6
#define KVR 2
#define NTOK (BATCH*SEQ)
#define NPROJ 832  // 800 padded to 13*64

typedef __bf16 bf16x8 __attribute__((ext_vector_type(8)));
typedef float f32x4 __attribute__((ext_vector_type(4)));
typedef unsigned short us8 __attribute__((ext_vector_type(8)));

__device__ inline unsigned short f2bf(float f){
  union { float f; unsigned int u; } v; v.f = f;
  unsigned int r = (v.u + 0x7fffu + ((v.u >> 16) & 1u)) >> 16;
  return (unsigned short)r;
}

// ---- cast f32 -> bf16, 4 elems/thread ----
__global__ void cast_kernel(const float* __restrict__ in, unsigned short* __restrict__ out, int n4){
  int i = blockIdx.x*blockDim.x + threadIdx.x;
  if (i >= n4) return;
  float4 v = ((const float4*)in)[i];
  ushort4 o; o.x = f2bf(v.x); o.y = f2bf(v.y); o.z = f2bf(v.z); o.w = f2bf(v.w);
  ((ushort4*)out)[i] = o;
}

// ---- build concatenated weight (832x1024 bf16) + bias (832 f32) ----
__global__ void build_wcat(const float* __restrict__ Waq, const float* __restrict__ Wak,
                           const float* __restrict__ Wav, const float* __restrict__ Wbq,
                           const float* __restrict__ Wbk, const float* __restrict__ Wbv,
                           const float* __restrict__ baq, const float* __restrict__ bak,
                           const float* __restrict__ bav, const float* __restrict__ bbq,
                           const float* __restrict__ bbk, const float* __restrict__ bbv,
                           unsigned short* __restrict__ Wcat, float* __restrict__ bcat){
  int n = blockIdx.x; int t = threadIdx.x;
  const float* src = nullptr; float bv_ = 0.f;
  if (n < 96)       { src = Waq + (size_t)n*DM;        bv_ = baq[n]; }
  else if (n < 128) { src = Wak + (size_t)(n-96)*DM;   bv_ = bak[n-96]; }
  else if (n < 160) { src = Wav + (size_t)(n-128)*DM;  bv_ = bav[n-128]; }
  else if (n < 544) { src = Wbq + (size_t)(n-160)*DM;  bv_ = bbq[n-160]; }
  else if (n < 672) { src = Wbk + (size_t)(n-544)*DM;  bv_ = bbk[n-544]; }
  else if (n < 800) { src = Wbv + (size_t)(n-672)*DM;  bv_ = bbv[n-672]; }
  unsigned short* dst = Wcat + (size_t)n*DM;
  if (src){
    float4 v = ((const float4*)src)[t];
    ushort4 o; o.x = f2bf(v.x); o.y = f2bf(v.y); o.z = f2bf(v.z); o.w = f2bf(v.w);
    ((ushort4*)dst)[t] = o;
  } else {
    ushort4 z = {0,0,0,0};
    ((ushort4*)dst)[t] = z;
  }
  if (t == 0) bcat[n] = bv_;
}

// ---- generic NT bf16 MFMA GEMM: C[M,N] = A[M,K] * Bw[N,K]^T + bias ----
__global__ __launch_bounds__(256) void gemm_nt(const unsigned short* __restrict__ A,
    const unsigned short* __restrict__ Bw, const float* __restrict__ bias,
    float* __restrict__ C, int M, int N, int K){
  __shared__ unsigned short As[64][72];
  __shared__ unsigned short Bs[64][72];
  int tid = threadIdx.x; int w = tid >> 6; int lane = tid & 63;
  int m0 = blockIdx.x*64, n0 = blockIdx.y*64;
  f32x4 acc[4] = {};
  int lr = tid >> 3;        // 0..31
  int lc = (tid & 7)*8;     // 0..56
  int row = w*16 + (lane & 15);
  int kb  = (lane >> 4)*8;
  for (int kt = 0; kt < K; kt += 64){
    us8 a0 = *(const us8*)(A  + (size_t)(m0+lr)*K    + kt + lc);
    us8 a1 = *(const us8*)(A  + (size_t)(m0+lr+32)*K + kt + lc);
    us8 b0 = *(const us8*)(Bw + (size_t)(n0+lr)*K    + kt + lc);
    us8 b1 = *(const us8*)(Bw + (size_t)(n0+lr+32)*K + kt + lc);
    __syncthreads();
    *(us8*)&As[lr][lc] = a0;    *(us8*)&As[lr+32][lc] = a1;
    *(us8*)&Bs[lr][lc] = b0;    *(us8*)&Bs[lr+32][lc] = b1;
    __syncthreads();
    bf16x8 af0 = *(const bf16x8*)&As[row][kb];
    bf16x8 af1 = *(const bf16x8*)&As[row][32+kb];
    #pragma unroll
    for (int nf = 0; nf < 4; ++nf){
      int col = nf*16 + (lane & 15);
      bf16x8 bf0 = *(const bf16x8*)&Bs[col][kb];
      bf16x8 bf1 = *(const bf16x8*)&Bs[col][32+kb];
      acc[nf] = __builtin_amdgcn_mfma_f32_16x16x32_bf16(af0, bf0, acc[nf], 0,0,0);
      acc[nf] = __builtin_amdgcn_mfma_f32_16x16x32_bf16(af1, bf1, acc[nf], 0,0,0);
    }
  }
  int rbase = w*16 + (lane >> 4)*4;
  #pragma unroll
  for (int nf = 0; nf < 4; ++nf){
    int col = n0 + nf*16 + (lane & 15);
    float bv_ = bias ? bias[col] : 0.f;
    #pragma unroll
    for (int r = 0; r < 4; ++r){
      C[(size_t)(m0 + rbase + r)*N + col] = acc[nf][r] + bv_;
    }
  }
}

// ---- RoPE + rank contraction: build Q,K,V (B,H,S,D) bf16; 1/8 folded into Q ----
__global__ __launch_bounds__(256) void qkv_kernel(const float* __restrict__ proj,
    const float* __restrict__ cosT, const float* __restrict__ sinT,
    unsigned short* __restrict__ Q, unsigned short* __restrict__ K,
    unsigned short* __restrict__ V){
  int token = blockIdx.x; int b = token >> 11; int s = token & 2047;
  const float* row = proj + (size_t)token*NPROJ;
  __shared__ float aq[96], ak[32], av[32], bq[QR][HD], bk[KVR][HD], bv[KVR][HD];
  int t = threadIdx.x;
  for (int i = t; i < 800; i += 256){
    float vv = row[i];
    if (i < 96) aq[i] = vv;
    else if (i < 128) ak[i-96] = vv;
    else if (i < 160) av[i-128] = vv;
    else if (i < 544) (&bq[0][0])[i-160] = vv;
    else if (i < 672) (&bk[0][0])[i-544] = vv;
    else (&bv[0][0])[i-672] = vv;
  }
  __syncthreads();
  {
    if (t < 192){
      int r = t >> 5, i = t & 31;
      float c = cosT[s*32+i], sn = sinT[s*32+i];
      float x1 = bq[r][2*i], x2 = bq[r][2*i+1];
      bq[r][2*i]   = x1*c - x2*sn;
      bq[r][2*i+1] = x1*sn + x2*c;
    } else {
      int r = (t-192) >> 5, i = t & 31;
      float c = cosT[s*32+i], sn = sinT[s*32+i];
      float x1 = bk[r][2*i], x2 = bk[r][2*i+1];
      bk[r][2*i]   = x1*c - x2*sn;
      bk[r][2*i+1] = x1*sn + x2*c;
    }
  }
  __syncthreads();
  int h = t >> 4; int dbase = (t & 15)*4;
  float qv[4] = {}, kv[4] = {}, vv[4] = {};
  #pragma unroll
  for (int r = 0; r < QR; ++r){
    float a = aq[h*QR + r];
    #pragma unroll
    for (int j = 0; j < 4; ++j) qv[j] += a * bq[r][dbase+j];
  }
  #pragma unroll
  for (int r = 0; r < KVR; ++r){
    float a1 = ak[h*KVR + r], a2 = av[h*KVR + r];
    #pragma unroll
    for (int j = 0; j < 4; ++j){ kv[j] += a1 * bk[r][dbase+j]; vv[j] += a2 * bv[r][dbase+j]; }
  }
  size_t base = ((size_t)(b*NH + h)*SEQ + s)*HD + dbase;
  ushort4 qo; qo.x=f2bf(qv[0]*0.125f); qo.y=f2bf(qv[1]*0.125f); qo.z=f2bf(qv[2]*0.125f); qo.w=f2bf(qv[3]*0.125f);
  ushort4 ko; ko.x=f2bf(kv[0]); ko.y=f2bf(kv[1]); ko.z=f2bf(kv[2]); ko.w=f2bf(kv[3]);
  ushort4 vo; vo.x=f2bf(vv[0]); vo.y=f2bf(vv[1]); vo.z=f2bf(vv[2]); vo.w=f2bf(vv[3]);
  *(ushort4*)(Q+base) = qo;
  *(ushort4*)(K+base) = ko;
  *(ushort4*)(V+base) = vo;
}

// ---- causal flash attention: grid (32 qblocks, 32 bh), 4 waves, 64 q-rows/block ----
__global__ __launch_bounds__(256) void attn_kernel(const unsigned short* __restrict__ Q,
   const unsigned short* __restrict__ K, const unsigned short* __restrict__ V,
   unsigned short* __restrict__ attnOut){
  int bh = blockIdx.y; int b = bh >> 4, h = bh & 15;
  int qblk = (int)(gridDim.x - 1) - (int)blockIdx.x;   // heavy blocks first
  int tid = threadIdx.x, w = tid >> 6, lane = tid & 63;
  const unsigned short* Qp = Q + (size_t)bh*SEQ*HD;
  const unsigned short* Kp = K + (size_t)bh*SEQ*HD;
  const unsigned short* Vp = V + (size_t)bh*SEQ*HD;
  __shared__ unsigned short Ks[32][72];
  __shared__ unsigned short Vt[64][40];
  __shared__ unsigned short Pw[4][16][40];
  int qrow = qblk*64 + w*16 + (lane & 15);
  int kb = (lane >> 4)*8;
  bf16x8 aq0 = *(const bf16x8*)(Qp + (size_t)qrow*HD + kb);
  bf16x8 aq1 = *(const bf16x8*)(Qp + (size_t)qrow*HD + 32 + kb);
  float m[4], l[4]; f32x4 o[4] = {};
  #pragma unroll
  for (int r = 0; r < 4; ++r){ m[r] = -1e30f; l[r] = 0.f; }
  int ntile = qblk*2 + 2;
  int sr = tid >> 3, sc = (tid & 7)*8;        // K staging: 32 rows x 8 chunks
  int sv = tid & 31, db = (tid >> 5)*8;       // V staging (transpose)
  for (int t = 0; t < ntile; ++t){
    us8 kvv = *(const us8*)(Kp + (size_t)(t*32 + sr)*HD + sc);
    us8 vvv = *(const us8*)(Vp + (size_t)(t*32 + sv)*HD + db);
    __syncthreads();   // all waves done reading prev tiles
    *(us8*)&Ks[sr][sc] = kvv;
    #pragma unroll
    for (int j = 0; j < 8; ++j) Vt[db+j][sv] = vvv[j];
    __syncthreads();
    f32x4 sf[2] = {};
    #pragma unroll
    for (int nf = 0; nf < 2; ++nf){
      bf16x8 bk0 = *(const bf16x8*)&Ks[nf*16 + (lane&15)][kb];
      bf16x8 bk1 = *(const bf16x8*)&Ks[nf*16 + (lane&15)][32+kb];
      sf[nf] = __builtin_amdgcn_mfma_f32_16x16x32_bf16(aq0, bk0, sf[nf], 0,0,0);
      sf[nf] = __builtin_amdgcn_mfma_f32_16x16x32_bf16(aq1, bk1, sf[nf], 0,0,0);
    }
    int colb = t*32;
    int rowb = qblk*64 + w*16 + ((lane>>4)*4);
    float p[2][4];
    #pragma unroll
    for (int r = 0; r < 4; ++r){
      int grow = rowb + r;
      float s0 = (colb +      (lane&15)) <= grow ? sf[0][r] : -1e30f;
      float s1 = (colb + 16 + (lane&15)) <= grow ? sf[1][r] : -1e30f;
      float cmax = fmaxf(s0, s1);
      cmax = fmaxf(cmax, __shfl_xor(cmax, 1));
      cmax = fmaxf(cmax, __shfl_xor(cmax, 2));
      cmax = fmaxf(cmax, __shfl_xor(cmax, 4));
      cmax = fmaxf(cmax, __shfl_xor(cmax, 8));
      float mn = fmaxf(m[r], cmax);
      float alpha = __expf(m[r] - mn);
      float p0 = __expf(s0 - mn), p1 = __expf(s1 - mn);
      float rs = p0 + p1;
      rs += __shfl_xor(rs, 1); rs += __shfl_xor(rs, 2);
      rs += __shfl_xor(rs, 4); rs += __shfl_xor(rs, 8);
      l[r] = l[r]*alpha + rs;
      m[r] = mn;
      #pragma unroll
      for (int nf = 0; nf < 4; ++nf) o[nf][r] *= alpha;
      p[0][r] = p0; p[1][r] = p1;
    }
    #pragma unroll
    for (int nf = 0; nf < 2; ++nf)
      #pragma unroll
      for (int r = 0; r < 4; ++r)
        Pw[w][(lane>>4)*4 + r][nf*16 + (lane&15)] = f2bf(p[nf][r]);
    bf16x8 pf = *(const bf16x8*)&Pw[w][lane&15][kb];
    #pragma unroll
    for (int nd = 0; nd < 4; ++nd){
      bf16x8 vf = *(const bf16x8*)&Vt[nd*16 + (lane&15)][kb];
      o[nd] = __builtin_amdgcn_mfma_f32_16x16x32_bf16(pf, vf, o[nd], 0,0,0);
    }
  }
  int srow = qblk*64 + w*16 + (lane>>4)*4;
  #pragma unroll
  for (int nd = 0; nd < 4; ++nd){
    int col = h*HD + nd*16 + (lane&15);
    #pragma unroll
    for (int r = 0; r < 4; ++r){
      float val = o[nd][r] / l[r];
      attnOut[((size_t)b*SEQ + (srow + r))*DM + col] = f2bf(val);
    }
  }
}

extern "C" void kernel_launch(void* const* d_in, const int* in_sizes, int n_in,
                              void* d_out, int out_size, void* d_ws, size_t ws_size,
                              hipStream_t stream){
  const float* x   = (const float*)d_in[0];
  const float* Waq = (const float*)d_in[1];
  const float* baq = (const float*)d_in[2];
  const float* Wbq = (const float*)d_in[3];
  const float* bbq = (const float*)d_in[4];
  const float* Wak = (const float*)d_in[5];
  const float* bak = (const float*)d_in[6];
  const float* Wbk = (const float*)d_in[7];
  const float* bbk = (const float*)d_in[8];
  const float* Wav = (const float*)d_in[9];
  const float* bav = (const float*)d_in[10];
  const float* Wbv = (const float*)d_in[11];
  const float* bbv = (const float*)d_in[12];
  const float* Wo  = (const float*)d_in[13];
  const float* bo  = (const float*)d_in[14];
  const float* cosT= (const float*)d_in[15];
  const float* sinT= (const float*)d_in[16];
  float* out = (float*)d_out;

  char* ws = (char*)d_ws;
  unsigned short* xb    = (unsigned short*)(ws + 0);          // 8.4 MB
  unsigned short* Wob   = (unsigned short*)(ws + 8388608);    // 2.1 MB
  unsigned short* Wcat  = (unsigned short*)(ws + 10485760);   // 1.7 MB
  float*          bcat  = (float*)(ws + 12189696);            // 3.3 KB
  float*          proj  = (float*)(ws + 12193280);            // 13.6 MB
  unsigned short* Qb    = (unsigned short*)(ws + 25824768);   // 8.4 MB
  unsigned short* Kb    = (unsigned short*)(ws + 34213376);   // 8.4 MB
  unsigned short* Vb    = (unsigned short*)(ws + 42601984);   // 8.4 MB
  unsigned short* attnB = (unsigned short*)(ws + 50990592);   // 8.4 MB

  cast_kernel<<<4096, 256, 0, stream>>>(x, xb, 1048576);
  cast_kernel<<<1024, 256, 0, stream>>>(Wo, Wob, 262144);
  build_wcat<<<832, 256, 0, stream>>>(Waq, Wak, Wav, Wbq, Wbk, Wbv,
                                      baq, bak, bav, bbq, bbk, bbv, Wcat, bcat);
  gemm_nt<<<dim3(64,13), 256, 0, stream>>>(xb, Wcat, bcat, proj, NTOK, NPROJ, DM);
  qkv_kernel<<<4096, 256, 0, stream>>>(proj, cosT, sinT, Qb, Kb, Vb);
  attn_kernel<<<dim3(32,32), 256, 0, stream>>>(Qb, Kb, Vb, attnB);
  gemm_nt<<<dim3(64,16), 256, 0, stream>>>(attnB, Wob, bo, out, NTOK, DM, DM);
}